// Round 7
// baseline (96.912 us; speedup 1.0000x reference)
//
#include <hip/hip_runtime.h>
#include <hip/hip_bf16.h>
#include <utility>

// out[131072,18] = theta(x)[131072,1330] @ (xi*mask)[1330,18]
// bf16 MFMA GEMM via mfma_f32_16x16x32_bf16.
// Order-4 symmetry rho = (0123)(4567)(89AB)(CDEF)(16 17): 1330 monomials ->
// 342 rep slots -> 43 K-chunks of 32. Lane-quad g evaluates the same
// compile-time rep expressions on rho^g-permuted inputs.
// Round-7: 1024-thread blocks, grid=256 = exactly 1 block/CU (no dispatch
// tail); W staged in LDS once per CU; tile1 zero-frags replace per-chunk
// v_and masking; 2 row-tiles per wave share every B fragment.

constexpr int NVARS   = 18;
constexpr int NOUT    = 18;
constexpr int NROWS   = 131072;
constexpr int PTERMS  = 1330;
constexpr int NCHUNKS = 43;             // K = 43*32 = 1376
constexpr int NSLOTS  = NCHUNKS * 8;    // 344 (342 used + 2 pad)

constexpr int WF0_SHORTS = NCHUNKS * 512;    // tile0 frags: 22016 shorts (44032 B)
constexpr int WF1_SHORTS = NCHUNKS * 12 * 8; // tile1: 12 frags/chunk (4g x {c16,c17,zero})
constexpr int WF_SHORTS  = WF0_SHORTS + WF1_SHORTS;  // 26144 shorts = 52288 B

typedef __attribute__((ext_vector_type(8))) short short8;
typedef __attribute__((ext_vector_type(4))) float f32x4;

struct T3 { int a, b, c; };   // sorted ascending; 18 = unused factor; 19 = pad

constexpr int rho1(int v) {
    if (v < 16)  return (v & ~3) | ((v + 1) & 3);
    if (v == 16) return 17;
    if (v == 17) return 16;
    return v;
}
constexpr int rho2v(int v) { return rho1(rho1(v)); }

constexpr T3 sort3(int u0, int u1, int u2) {
    int t = 0;
    if (u0 > u1) { t = u0; u0 = u1; u1 = t; }
    if (u1 > u2) { t = u1; u1 = u2; u2 = t; }
    if (u0 > u1) { t = u0; u0 = u1; u1 = t; }
    return T3{u0, u1, u2};
}
constexpr T3 rho3(T3 t) { return sort3(rho1(t.a), rho1(t.b), rho1(t.c)); }

constexpr bool t3_less(T3 x, T3 y) {
    if (x.a != y.a) return x.a < y.a;
    if (x.b != y.b) return x.b < y.b;
    return x.c < y.c;
}
constexpr bool t3_eq(T3 x, T3 y) { return x.a == y.a && x.b == y.b && x.c == y.c; }

constexpr int rank_of(T3 t) {
    int deg = (t.a < 18) + (t.b < 18) + (t.c < 18);
    if (deg == 0) return 0;
    if (deg == 1) return 1 + t.a;
    if (deg == 2) {
        int r = 19;
        for (int a = 0; a < t.a; ++a) r += 18 - a;
        return r + (t.b - t.a);
    }
    int r = 190;
    for (int a = 0; a < t.a; ++a) { int n = 18 - a; r += n * (n + 1) / 2; }
    for (int b = t.a; b < t.b; ++b) r += 18 - b;
    return r + (t.c - t.b);
}

struct RepTables {
    signed char va[NSLOTS], vb[NSLOTS], vc[NSLOTS];
    short p[4][NSLOTS];   // flat term index for group g's k-position; -1 => zero W
    int count;
};

constexpr void consider(RepTables& R, int& s, T3 t) {
    T3 im[4] = {t, T3{0, 0, 0}, T3{0, 0, 0}, T3{0, 0, 0}};
    im[1] = rho3(im[0]);
    im[2] = rho3(im[1]);
    im[3] = rho3(im[2]);
    for (int g = 1; g < 4; ++g)
        if (t3_less(im[g], t)) return;   // not the orbit representative
    R.va[s] = (signed char)t.a; R.vb[s] = (signed char)t.b; R.vc[s] = (signed char)t.c;
    for (int g = 0; g < 4; ++g) {
        bool dup = false;
        for (int h = 0; h < g; ++h)
            if (t3_eq(im[h], im[g])) dup = true;
        R.p[g][s] = dup ? (short)-1 : (short)rank_of(im[g]);
    }
    ++s;
}

constexpr RepTables make_tables() {
    RepTables R{};
    int s = 0;
    consider(R, s, T3{18, 18, 18});
    for (int a = 0; a < NVARS; ++a) consider(R, s, T3{a, 18, 18});
    for (int a = 0; a < NVARS; ++a)
        for (int b = a; b < NVARS; ++b) consider(R, s, T3{a, b, 18});
    for (int a = 0; a < NVARS; ++a)
        for (int b = a; b < NVARS; ++b)
            for (int c = b; c < NVARS; ++c) consider(R, s, T3{a, b, c});
    R.count = s;
    for (; s < NSLOTS; ++s) {
        R.va[s] = 19; R.vb[s] = 19; R.vc[s] = 19;
        for (int g = 0; g < 4; ++g) R.p[g][s] = -1;
    }
    return R;
}

constexpr RepTables h_tab = make_tables();          // compile-time use
static_assert(h_tab.count == 342, "orbit enumeration must give 342 rep slots");
__device__ const RepTables d_tab = make_tables();   // runtime use (prep)

// ---- bf16 pair pack --------------------------------------------------------

#if __has_builtin(__builtin_amdgcn_cvt_pk_bf16_f32)
typedef __bf16 bf16x2 __attribute__((ext_vector_type(2)));
__device__ __forceinline__ unsigned pack2(float f0, float f1) {
    bf16x2 r = __builtin_amdgcn_cvt_pk_bf16_f32(f0, f1);   // lo=f0, hi=f1, RNE
    return __builtin_bit_cast(unsigned, r);
}
#else
__device__ __forceinline__ unsigned pack2(float f0, float f1) {
    unsigned u0 = __float_as_uint(f0) + 0x8000u;
    unsigned u1 = __float_as_uint(f1) + 0x8000u;
    return __builtin_amdgcn_perm(u1, u0, 0x07060302u);     // lo=bf16(f0), hi=bf16(f1)
}
#endif

// ---- main kernel -----------------------------------------------------------

template <int S>
__device__ __forceinline__ float term_val(const float (&x)[NVARS]) {
    constexpr int a = h_tab.va[S], b = h_tab.vb[S], c = h_tab.vc[S];
    if constexpr (a >= 19)      return 0.0f;                 // pad slot
    else if constexpr (a == 18) return 1.0f;                 // constant
    else if constexpr (b == 18) return x[a];
    else if constexpr (c == 18) return x[a] * x[b];
    else                        return x[a] * x[b] * x[c];
}

union AFrag { unsigned u[4]; short8 v; };

template <int CI, int... I>
__device__ __forceinline__ void eval8(const float (&x)[NVARS], float (&t)[8],
                                      std::integer_sequence<int, I...>) {
    ((t[I] = term_val<CI * 8 + I>(x)), ...);
}

template <int CI>
__device__ __forceinline__ void kstep(const float (&xA)[NVARS], const float (&xB)[NVARS],
                                      const short* p0, const short* p1,
                                      f32x4& acc00, f32x4& acc01,
                                      f32x4& acc10, f32x4& acc11) {
    float tA[8], tB[8];
    eval8<CI>(xA, tA, std::make_integer_sequence<int, 8>{});
    eval8<CI>(xB, tB, std::make_integer_sequence<int, 8>{});
    AFrag afA, afB;
#pragma unroll
    for (int j = 0; j < 4; ++j) {
        afA.u[j] = pack2(tA[2 * j], tA[2 * j + 1]);
        afB.u[j] = pack2(tB[2 * j], tB[2 * j + 1]);
    }
    short8 b0 = *(const short8*)(p0 + CI * 512);      // tile0 frag
    short8 b1 = *(const short8*)(p1 + CI * (12 * 8)); // tile1 frag (zero frag if n>=2)
    acc00 = __builtin_amdgcn_mfma_f32_16x16x32_bf16(afA.v, b0, acc00, 0, 0, 0);
    acc10 = __builtin_amdgcn_mfma_f32_16x16x32_bf16(afB.v, b0, acc10, 0, 0, 0);
    acc01 = __builtin_amdgcn_mfma_f32_16x16x32_bf16(afA.v, b1, acc01, 0, 0, 0);
    acc11 = __builtin_amdgcn_mfma_f32_16x16x32_bf16(afB.v, b1, acc11, 0, 0, 0);
}

template <int... CI>
__device__ __forceinline__ void kloop(const float (&xA)[NVARS], const float (&xB)[NVARS],
                                      const short* p0, const short* p1,
                                      f32x4& acc00, f32x4& acc01,
                                      f32x4& acc10, f32x4& acc11,
                                      std::integer_sequence<int, CI...>) {
    (kstep<CI>(xA, xB, p0, p1, acc00, acc01, acc10, acc11), ...);
}

__device__ __forceinline__ void load_x(const float* __restrict__ z,
                                       const float* __restrict__ betas,
                                       int arow, bool s1, bool s2, float (&x)[NVARS]) {
    float x0[NVARS];
    const float4* z4 = (const float4*)(z + (size_t)arow * 16);
    float4 v0 = z4[0], v1 = z4[1], v2 = z4[2], v3 = z4[3];
    x0[0]  = v0.x; x0[1]  = v0.y; x0[2]  = v0.z; x0[3]  = v0.w;
    x0[4]  = v1.x; x0[5]  = v1.y; x0[6]  = v1.z; x0[7]  = v1.w;
    x0[8]  = v2.x; x0[9]  = v2.y; x0[10] = v2.z; x0[11] = v2.w;
    x0[12] = v3.x; x0[13] = v3.y; x0[14] = v3.z; x0[15] = v3.w;
    const float2 b2 = *(const float2*)(betas + (size_t)arow * 2);
    x0[16] = b2.x; x0[17] = b2.y;
    float y[NVARS];
#pragma unroll
    for (int v = 0; v < NVARS; ++v) y[v] = s1 ? x0[rho1(v)] : x0[v];
#pragma unroll
    for (int v = 0; v < NVARS; ++v) x[v] = s2 ? y[rho2v(v)] : y[v];
}

__global__ __launch_bounds__(1024, 4) void vindy_mfma(const float* __restrict__ z,
                                                      const float* __restrict__ betas,
                                                      const short* __restrict__ wf,
                                                      float* __restrict__ out) {
    __shared__ __align__(16) short ldsW[WF_SHORTS];   // 52288 B -> 1 block/CU
    // stage all W fragments once per block (flat 16B copies, fully coalesced)
    {
        const float4* src = (const float4*)wf;
        float4* dst = (float4*)ldsW;
        for (int i = threadIdx.x; i < WF_SHORTS / 8; i += 1024) dst[i] = src[i];
    }
    __syncthreads();

    const int lane = threadIdx.x & 63;
    const int wave = threadIdx.x >> 6;
    const int g    = lane >> 4;        // rho-power / k-quad
    const int n    = lane & 15;        // A-row within tile; C col
    const int rowbase = blockIdx.x * 512 + wave * 32;

    const bool s1 = (g & 1) != 0;
    const bool s2 = (g & 2) != 0;
    float xA[NVARS], xB[NVARS];
    load_x(z, betas, rowbase + n,      s1, s2, xA);
    load_x(z, betas, rowbase + 16 + n, s1, s2, xB);

    const short* p0 = ldsW + lane * 8;                                   // tile0 base
    const short* p1 = ldsW + WF0_SHORTS + (g * 3 + (n < 2 ? n : 2)) * 8; // tile1/zero

    f32x4 acc00, acc01, acc10, acc11;
#pragma unroll
    for (int i = 0; i < 4; ++i) { acc00[i] = 0.0f; acc01[i] = 0.0f; acc10[i] = 0.0f; acc11[i] = 0.0f; }

    kloop(xA, xB, p0, p1, acc00, acc01, acc10, acc11,
          std::make_integer_sequence<int, NCHUNKS>{});

    // C/D 16x16 layout: col = lane&15, row = g*4 + reg
    float* o0 = out + (size_t)(rowbase + g * 4) * NOUT;
    float* o1 = out + (size_t)(rowbase + 16 + g * 4) * NOUT;
#pragma unroll
    for (int r = 0; r < 4; ++r) {
        o0[(size_t)r * NOUT + n] = acc00[r];
        o1[(size_t)r * NOUT + n] = acc10[r];
    }
    if (n < 2) {
#pragma unroll
        for (int r = 0; r < 4; ++r) {
            o0[(size_t)r * NOUT + 16 + n] = acc01[r];
            o1[(size_t)r * NOUT + 16 + n] = acc11[r];
        }
    }
}

// ---- prep: W fragments in staged layout ------------------------------------
// region 0 (tile0, cols 0-15): wf[c*512 + l*8 + j] = W[p[l>>4][c*8+j]][l&15]
// region 1 (tile1): 12 frags/chunk, frag q = g*3+qq; qq<2 -> col 16+qq,
//                   qq==2 -> zeros. wf[WF0 + c*96 + q*8 + j]

__global__ void prep_wfrag(const float* __restrict__ xi, const float* __restrict__ mask,
                           __hip_bfloat16* __restrict__ wf) {
    int i = blockIdx.x * blockDim.x + threadIdx.x;
    if (i >= WF_SHORTS) return;
    int p = -1, col = 0;
    if (i < WF0_SHORTS) {
        int j = i & 7, l = (i >> 3) & 63, c = i >> 9;
        col = l & 15;
        p = d_tab.p[l >> 4][c * 8 + j];
    } else {
        int i2 = i - WF0_SHORTS;
        int j = i2 & 7;
        int q = (i2 >> 3) % 12;
        int c = i2 / 96;
        int qq = q % 3, gg = q / 3;
        if (qq < 2) {
            col = 16 + qq;
            p = d_tab.p[gg][c * 8 + j];
        }   // qq==2: zero frag (p stays -1)
    }
    float v = 0.0f;
    if (p >= 0) v = xi[p * NOUT + col] * mask[p * NOUT + col];
    wf[i] = __float2bfloat16(v);
}

extern "C" void kernel_launch(void* const* d_in, const int* in_sizes, int n_in,
                              void* d_out, int out_size, void* d_ws, size_t ws_size,
                              hipStream_t stream) {
    const float* z     = (const float*)d_in[0];
    const float* betas = (const float*)d_in[1];
    const float* xi    = (const float*)d_in[2];
    const float* mask  = (const float*)d_in[3];
    __hip_bfloat16* wf = (__hip_bfloat16*)d_ws;   // 52288 bytes
    float* out = (float*)d_out;

    prep_wfrag<<<(WF_SHORTS + 255) / 256, 256, 0, stream>>>(xi, mask, wf);
    vindy_mfma<<<NROWS / 512, 1024, 0, stream>>>(z, betas, (const short*)d_ws, out);
}

// Round 8
// 96.734 us; speedup vs baseline: 1.0018x; 1.0018x over previous
//
#include <hip/hip_runtime.h>
#include <hip/hip_bf16.h>
#include <utility>

// out[131072,18] = theta(x)[131072,1330] @ (xi*mask)[1330,18]
// bf16 MFMA GEMM via mfma_f32_16x16x32_bf16.
// Order-4 symmetry rho = (0123)(4567)(89AB)(CDEF)(16 17): 1330 monomials ->
// 342 rep slots -> 43 K-chunks of 32. Lane-quad g evaluates the same
// compile-time rep expressions on rho^g-permuted inputs.
// Round-8: identical to round-7 EXCEPT __launch_bounds__(1024) with no
// waves-per-EU arg. r7's (1024,4) squeezed the allocator to 64 VGPR ->
// ~49 MB scratch spill traffic (WRITE_SIZE 58.6 MB vs 9.2 MB output).
// A 1024-thread block needs 4 waves/SIMD resident -> cap 128 VGPR, enough
// for the ~95 live values. Grid=256 = 1 block/CU, W LDS-resident, no tail.

constexpr int NVARS   = 18;
constexpr int NOUT    = 18;
constexpr int NROWS   = 131072;
constexpr int PTERMS  = 1330;
constexpr int NCHUNKS = 43;             // K = 43*32 = 1376
constexpr int NSLOTS  = NCHUNKS * 8;    // 344 (342 used + 2 pad)

constexpr int WF0_SHORTS = NCHUNKS * 512;    // tile0 frags: 22016 shorts (44032 B)
constexpr int WF1_SHORTS = NCHUNKS * 12 * 8; // tile1: 12 frags/chunk (4g x {c16,c17,zero})
constexpr int WF_SHORTS  = WF0_SHORTS + WF1_SHORTS;  // 26144 shorts = 52288 B

typedef __attribute__((ext_vector_type(8))) short short8;
typedef __attribute__((ext_vector_type(4))) float f32x4;

struct T3 { int a, b, c; };   // sorted ascending; 18 = unused factor; 19 = pad

constexpr int rho1(int v) {
    if (v < 16)  return (v & ~3) | ((v + 1) & 3);
    if (v == 16) return 17;
    if (v == 17) return 16;
    return v;
}
constexpr int rho2v(int v) { return rho1(rho1(v)); }

constexpr T3 sort3(int u0, int u1, int u2) {
    int t = 0;
    if (u0 > u1) { t = u0; u0 = u1; u1 = t; }
    if (u1 > u2) { t = u1; u1 = u2; u2 = t; }
    if (u0 > u1) { t = u0; u0 = u1; u1 = t; }
    return T3{u0, u1, u2};
}
constexpr T3 rho3(T3 t) { return sort3(rho1(t.a), rho1(t.b), rho1(t.c)); }

constexpr bool t3_less(T3 x, T3 y) {
    if (x.a != y.a) return x.a < y.a;
    if (x.b != y.b) return x.b < y.b;
    return x.c < y.c;
}
constexpr bool t3_eq(T3 x, T3 y) { return x.a == y.a && x.b == y.b && x.c == y.c; }

constexpr int rank_of(T3 t) {
    int deg = (t.a < 18) + (t.b < 18) + (t.c < 18);
    if (deg == 0) return 0;
    if (deg == 1) return 1 + t.a;
    if (deg == 2) {
        int r = 19;
        for (int a = 0; a < t.a; ++a) r += 18 - a;
        return r + (t.b - t.a);
    }
    int r = 190;
    for (int a = 0; a < t.a; ++a) { int n = 18 - a; r += n * (n + 1) / 2; }
    for (int b = t.a; b < t.b; ++b) r += 18 - b;
    return r + (t.c - t.b);
}

struct RepTables {
    signed char va[NSLOTS], vb[NSLOTS], vc[NSLOTS];
    short p[4][NSLOTS];   // flat term index for group g's k-position; -1 => zero W
    int count;
};

constexpr void consider(RepTables& R, int& s, T3 t) {
    T3 im[4] = {t, T3{0, 0, 0}, T3{0, 0, 0}, T3{0, 0, 0}};
    im[1] = rho3(im[0]);
    im[2] = rho3(im[1]);
    im[3] = rho3(im[2]);
    for (int g = 1; g < 4; ++g)
        if (t3_less(im[g], t)) return;   // not the orbit representative
    R.va[s] = (signed char)t.a; R.vb[s] = (signed char)t.b; R.vc[s] = (signed char)t.c;
    for (int g = 0; g < 4; ++g) {
        bool dup = false;
        for (int h = 0; h < g; ++h)
            if (t3_eq(im[h], im[g])) dup = true;
        R.p[g][s] = dup ? (short)-1 : (short)rank_of(im[g]);
    }
    ++s;
}

constexpr RepTables make_tables() {
    RepTables R{};
    int s = 0;
    consider(R, s, T3{18, 18, 18});
    for (int a = 0; a < NVARS; ++a) consider(R, s, T3{a, 18, 18});
    for (int a = 0; a < NVARS; ++a)
        for (int b = a; b < NVARS; ++b) consider(R, s, T3{a, b, 18});
    for (int a = 0; a < NVARS; ++a)
        for (int b = a; b < NVARS; ++b)
            for (int c = b; c < NVARS; ++c) consider(R, s, T3{a, b, c});
    R.count = s;
    for (; s < NSLOTS; ++s) {
        R.va[s] = 19; R.vb[s] = 19; R.vc[s] = 19;
        for (int g = 0; g < 4; ++g) R.p[g][s] = -1;
    }
    return R;
}

constexpr RepTables h_tab = make_tables();          // compile-time use
static_assert(h_tab.count == 342, "orbit enumeration must give 342 rep slots");
__device__ const RepTables d_tab = make_tables();   // runtime use (prep)

// ---- bf16 pair pack --------------------------------------------------------

#if __has_builtin(__builtin_amdgcn_cvt_pk_bf16_f32)
typedef __bf16 bf16x2 __attribute__((ext_vector_type(2)));
__device__ __forceinline__ unsigned pack2(float f0, float f1) {
    bf16x2 r = __builtin_amdgcn_cvt_pk_bf16_f32(f0, f1);   // lo=f0, hi=f1, RNE
    return __builtin_bit_cast(unsigned, r);
}
#else
__device__ __forceinline__ unsigned pack2(float f0, float f1) {
    unsigned u0 = __float_as_uint(f0) + 0x8000u;
    unsigned u1 = __float_as_uint(f1) + 0x8000u;
    return __builtin_amdgcn_perm(u1, u0, 0x07060302u);     // lo=bf16(f0), hi=bf16(f1)
}
#endif

// ---- main kernel -----------------------------------------------------------

template <int S>
__device__ __forceinline__ float term_val(const float (&x)[NVARS]) {
    constexpr int a = h_tab.va[S], b = h_tab.vb[S], c = h_tab.vc[S];
    if constexpr (a >= 19)      return 0.0f;                 // pad slot
    else if constexpr (a == 18) return 1.0f;                 // constant
    else if constexpr (b == 18) return x[a];
    else if constexpr (c == 18) return x[a] * x[b];
    else                        return x[a] * x[b] * x[c];
}

union AFrag { unsigned u[4]; short8 v; };

template <int CI, int... I>
__device__ __forceinline__ void eval8(const float (&x)[NVARS], float (&t)[8],
                                      std::integer_sequence<int, I...>) {
    ((t[I] = term_val<CI * 8 + I>(x)), ...);
}

template <int CI>
__device__ __forceinline__ void kstep(const float (&xA)[NVARS], const float (&xB)[NVARS],
                                      const short* p0, const short* p1,
                                      f32x4& acc00, f32x4& acc01,
                                      f32x4& acc10, f32x4& acc11) {
    float tA[8], tB[8];
    eval8<CI>(xA, tA, std::make_integer_sequence<int, 8>{});
    eval8<CI>(xB, tB, std::make_integer_sequence<int, 8>{});
    AFrag afA, afB;
#pragma unroll
    for (int j = 0; j < 4; ++j) {
        afA.u[j] = pack2(tA[2 * j], tA[2 * j + 1]);
        afB.u[j] = pack2(tB[2 * j], tB[2 * j + 1]);
    }
    short8 b0 = *(const short8*)(p0 + CI * 512);      // tile0 frag
    short8 b1 = *(const short8*)(p1 + CI * (12 * 8)); // tile1 frag (zero frag if n>=2)
    acc00 = __builtin_amdgcn_mfma_f32_16x16x32_bf16(afA.v, b0, acc00, 0, 0, 0);
    acc10 = __builtin_amdgcn_mfma_f32_16x16x32_bf16(afB.v, b0, acc10, 0, 0, 0);
    acc01 = __builtin_amdgcn_mfma_f32_16x16x32_bf16(afA.v, b1, acc01, 0, 0, 0);
    acc11 = __builtin_amdgcn_mfma_f32_16x16x32_bf16(afB.v, b1, acc11, 0, 0, 0);
}

template <int... CI>
__device__ __forceinline__ void kloop(const float (&xA)[NVARS], const float (&xB)[NVARS],
                                      const short* p0, const short* p1,
                                      f32x4& acc00, f32x4& acc01,
                                      f32x4& acc10, f32x4& acc11,
                                      std::integer_sequence<int, CI...>) {
    (kstep<CI>(xA, xB, p0, p1, acc00, acc01, acc10, acc11), ...);
}

__device__ __forceinline__ void load_x(const float* __restrict__ z,
                                       const float* __restrict__ betas,
                                       int arow, bool s1, bool s2, float (&x)[NVARS]) {
    float x0[NVARS];
    const float4* z4 = (const float4*)(z + (size_t)arow * 16);
    float4 v0 = z4[0], v1 = z4[1], v2 = z4[2], v3 = z4[3];
    x0[0]  = v0.x; x0[1]  = v0.y; x0[2]  = v0.z; x0[3]  = v0.w;
    x0[4]  = v1.x; x0[5]  = v1.y; x0[6]  = v1.z; x0[7]  = v1.w;
    x0[8]  = v2.x; x0[9]  = v2.y; x0[10] = v2.z; x0[11] = v2.w;
    x0[12] = v3.x; x0[13] = v3.y; x0[14] = v3.z; x0[15] = v3.w;
    const float2 b2 = *(const float2*)(betas + (size_t)arow * 2);
    x0[16] = b2.x; x0[17] = b2.y;
    float y[NVARS];
#pragma unroll
    for (int v = 0; v < NVARS; ++v) y[v] = s1 ? x0[rho1(v)] : x0[v];
#pragma unroll
    for (int v = 0; v < NVARS; ++v) x[v] = s2 ? y[rho2v(v)] : y[v];
}

__global__ __launch_bounds__(1024) void vindy_mfma(const float* __restrict__ z,
                                                   const float* __restrict__ betas,
                                                   const short* __restrict__ wf,
                                                   float* __restrict__ out) {
    __shared__ __align__(16) short ldsW[WF_SHORTS];   // 52288 B -> 1 block/CU
    // stage all W fragments once per block (flat 16B copies, fully coalesced)
    {
        const float4* src = (const float4*)wf;
        float4* dst = (float4*)ldsW;
        for (int i = threadIdx.x; i < WF_SHORTS / 8; i += 1024) dst[i] = src[i];
    }
    __syncthreads();

    const int lane = threadIdx.x & 63;
    const int wave = threadIdx.x >> 6;
    const int g    = lane >> 4;        // rho-power / k-quad
    const int n    = lane & 15;        // A-row within tile; C col
    const int rowbase = blockIdx.x * 512 + wave * 32;

    const bool s1 = (g & 1) != 0;
    const bool s2 = (g & 2) != 0;
    float xA[NVARS], xB[NVARS];
    load_x(z, betas, rowbase + n,      s1, s2, xA);
    load_x(z, betas, rowbase + 16 + n, s1, s2, xB);

    const short* p0 = ldsW + lane * 8;                                   // tile0 base
    const short* p1 = ldsW + WF0_SHORTS + (g * 3 + (n < 2 ? n : 2)) * 8; // tile1/zero

    f32x4 acc00, acc01, acc10, acc11;
#pragma unroll
    for (int i = 0; i < 4; ++i) { acc00[i] = 0.0f; acc01[i] = 0.0f; acc10[i] = 0.0f; acc11[i] = 0.0f; }

    kloop(xA, xB, p0, p1, acc00, acc01, acc10, acc11,
          std::make_integer_sequence<int, NCHUNKS>{});

    // C/D 16x16 layout: col = lane&15, row = g*4 + reg
    float* o0 = out + (size_t)(rowbase + g * 4) * NOUT;
    float* o1 = out + (size_t)(rowbase + 16 + g * 4) * NOUT;
#pragma unroll
    for (int r = 0; r < 4; ++r) {
        o0[(size_t)r * NOUT + n] = acc00[r];
        o1[(size_t)r * NOUT + n] = acc10[r];
    }
    if (n < 2) {
#pragma unroll
        for (int r = 0; r < 4; ++r) {
            o0[(size_t)r * NOUT + 16 + n] = acc01[r];
            o1[(size_t)r * NOUT + 16 + n] = acc11[r];
        }
    }
}

// ---- prep: W fragments in staged layout ------------------------------------
// region 0 (tile0, cols 0-15): wf[c*512 + l*8 + j] = W[p[l>>4][c*8+j]][l&15]
// region 1 (tile1): 12 frags/chunk, frag q = g*3+qq; qq<2 -> col 16+qq,
//                   qq==2 -> zeros. wf[WF0 + c*96 + q*8 + j]

__global__ void prep_wfrag(const float* __restrict__ xi, const float* __restrict__ mask,
                           __hip_bfloat16* __restrict__ wf) {
    int i = blockIdx.x * blockDim.x + threadIdx.x;
    if (i >= WF_SHORTS) return;
    int p = -1, col = 0;
    if (i < WF0_SHORTS) {
        int j = i & 7, l = (i >> 3) & 63, c = i >> 9;
        col = l & 15;
        p = d_tab.p[l >> 4][c * 8 + j];
    } else {
        int i2 = i - WF0_SHORTS;
        int j = i2 & 7;
        int q = (i2 >> 3) % 12;
        int c = i2 / 96;
        int qq = q % 3, gg = q / 3;
        if (qq < 2) {
            col = 16 + qq;
            p = d_tab.p[gg][c * 8 + j];
        }   // qq==2: zero frag (p stays -1)
    }
    float v = 0.0f;
    if (p >= 0) v = xi[p * NOUT + col] * mask[p * NOUT + col];
    wf[i] = __float2bfloat16(v);
}

extern "C" void kernel_launch(void* const* d_in, const int* in_sizes, int n_in,
                              void* d_out, int out_size, void* d_ws, size_t ws_size,
                              hipStream_t stream) {
    const float* z     = (const float*)d_in[0];
    const float* betas = (const float*)d_in[1];
    const float* xi    = (const float*)d_in[2];
    const float* mask  = (const float*)d_in[3];
    __hip_bfloat16* wf = (__hip_bfloat16*)d_ws;   // 52288 bytes
    float* out = (float*)d_out;

    prep_wfrag<<<(WF_SHORTS + 255) / 256, 256, 0, stream>>>(xi, mask, wf);
    vindy_mfma<<<NROWS / 512, 1024, 0, stream>>>(z, betas, (const short*)d_ws, out);
}